// Round 1
// baseline (673.274 us; speedup 1.0000x reference)
//
#include <hip/hip_runtime.h>

// NSA constants
#define NCMP 127
#define SCALE 0.08838834764831845f
#define TWG 8

typedef __attribute__((ext_vector_type(8))) short bf16x8;
typedef __attribute__((ext_vector_type(4))) float f32x4;

__device__ __forceinline__ unsigned short f2bf(float x) {
    union { float f; unsigned u; } a; a.f = x;
    unsigned r = a.u + 0x7fffu + ((a.u >> 16) & 1u);
    return (unsigned short)(r >> 16);
}

// ---------------- Kernel A: compress (gate-pooled blocks) ----------------
__global__ __launch_bounds__(256) void k_compress(const float* __restrict__ src,
                                                  const float* __restrict__ w,
                                                  float* __restrict__ out) {
    __shared__ float blk[4096];   // 32 x 128
    __shared__ float gate[32];
    int n = blockIdx.x;
    int tid = threadIdx.x;
    const float* sp = src + n * 16 * 128;
    for (int i = tid; i < 4096; i += 256) blk[i] = sp[i];
    __syncthreads();
    int wv = tid >> 6, ln = tid & 63;
    for (int jj = 0; jj < 8; ++jj) {
        int j = wv * 8 + jj;
        const float* wp = w + j * 4096;
        float s = 0.f;
        for (int e = ln; e < 4096; e += 64) s += blk[e] * wp[e];
        #pragma unroll
        for (int off = 32; off > 0; off >>= 1) s += __shfl_xor(s, off);
        if (ln == 0) gate[j] = s;
    }
    __syncthreads();
    if (tid == 0) {
        float m = gate[0];
        for (int j = 1; j < 32; ++j) m = fmaxf(m, gate[j]);
        float ss = 0.f;
        for (int j = 0; j < 32; ++j) ss += expf(gate[j] - m);
        float inv = 1.f / ss;
        for (int j = 0; j < 32; ++j) gate[j] = expf(gate[j] - m) * inv;
    }
    __syncthreads();
    if (tid < 128) {
        float acc = 0.f;
        for (int kk = 0; kk < 32; ++kk) acc += gate[kk] * blk[kk * 128 + tid];
        out[n * 128 + tid] = acc;
    }
}

// ---------- Kernel B: compressed attention + top-k block select ----------
__global__ __launch_bounds__(256) void k_cmp_attn(const float* __restrict__ q,
                                                  const float* __restrict__ ck,
                                                  const float* __restrict__ cv,
                                                  float* __restrict__ o_cmp,
                                                  unsigned int* __restrict__ selmask) {
    __shared__ float qs[1024];
    __shared__ float sc[8][128];
    __shared__ float pg[128];
    __shared__ float slc[32];
    __shared__ float adj[32];
    int t = blockIdx.x, tid = threadIdx.x;
    for (int i = tid; i < 1024; i += 256) qs[i] = q[t * 1024 + i];
    int nvalid = (t >= 31) ? (((t - 31) >> 4) + 1) : 0;
    if (nvalid > NCMP) nvalid = NCMP;
    __syncthreads();
    // scores: 8 heads x 127 blocks
    for (int idx = tid; idx < 8 * NCMP; idx += 256) {
        int h = idx / NCMP, n = idx % NCMP;
        float s = 0.f;
        if (n < nvalid) {
            const float* qp = qs + h * 128;
            const float* kp = ck + n * 128;
            for (int d = 0; d < 128; ++d) s += qp[d] * kp[d];
            s *= SCALE;
        }
        sc[h][n] = s;
    }
    __syncthreads();
    // per-head softmax (wave wv handles heads 2wv, 2wv+1; rows disjoint)
    int wv = tid >> 6, ln = tid & 63;
    for (int hh = 0; hh < 2; ++hh) {
        int h = wv * 2 + hh;
        float m = -3e38f;
        for (int n2 = ln; n2 < nvalid; n2 += 64) m = fmaxf(m, sc[h][n2]);
        #pragma unroll
        for (int off = 32; off > 0; off >>= 1) m = fmaxf(m, __shfl_xor(m, off));
        float ss = 0.f;
        for (int n2 = ln; n2 < nvalid; n2 += 64) ss += expf(sc[h][n2] - m);
        #pragma unroll
        for (int off = 32; off > 0; off >>= 1) ss += __shfl_xor(ss, off);
        float inv = (ss > 0.f) ? 1.f / ss : 0.f;
        for (int n2 = ln; n2 < NCMP; n2 += 64)
            sc[h][n2] = (n2 < nvalid) ? expf(sc[h][n2] - m) * inv : 0.f;
    }
    __syncthreads();
    // o_cmp (written into d_out; k_main reads then overwrites same elements)
    {
        int h = tid >> 5, d0 = (tid & 31) << 2;
        float a0 = 0, a1 = 0, a2 = 0, a3 = 0;
        for (int n2 = 0; n2 < nvalid; ++n2) {
            float p = sc[h][n2];
            const float* vp = cv + n2 * 128 + d0;
            a0 += p * vp[0]; a1 += p * vp[1]; a2 += p * vp[2]; a3 += p * vp[3];
        }
        float* op = o_cmp + t * 1024 + h * 128 + d0;
        op[0] = a0; op[1] = a1; op[2] = a2; op[3] = a3;
    }
    if (tid < NCMP) {
        float s = 0.f;
        for (int h = 0; h < 8; ++h) s += sc[h][tid];
        pg[tid] = s;
    }
    __syncthreads();
    if (tid < 32) {
        float s = 0.f;
        int n0 = tid * 4, n1 = n0 + 4; if (n1 > NCMP) n1 = NCMP;
        for (int n2 = n0; n2 < n1; ++n2) s += pg[n2];
        slc[tid] = s;
    }
    __syncthreads();
    if (tid == 0) {
        int qblk = t >> 6;
        for (int s = 0; s < 32; ++s) {
            if (s > qblk) adj[s] = -1e30f;
            else adj[s] = slc[s] + ((s == 0 || s > qblk - 2) ? 1e30f : 0.f);
        }
        unsigned int msk = 0u;
        for (int it = 0; it < 16; ++it) {
            float best = -2e38f; int bi = 0;
            for (int s = 0; s < 32; ++s) { if (adj[s] > best) { best = adj[s]; bi = s; } }
            if (best <= -5e29f) break;      // valid = topv > NEG/2
            msk |= 1u << bi;
            adj[bi] = -2e38f;
        }
        selmask[t] = msk;
    }
}

// -------- Kernel C: select + sliding-window attention + gate fusion --------
__global__ __launch_bounds__(256) void k_main(const float* __restrict__ q,
                                              const float* __restrict__ k,
                                              const float* __restrict__ v,
                                              const unsigned int* __restrict__ selmask,
                                              const float* __restrict__ fw,
                                              float* __restrict__ out) {
    __shared__ unsigned short k_lds[64 * 136];      // bf16 row-major, stride 136
    __shared__ unsigned short vt_lds[128 * 72];     // bf16 transposed vt[n][p], stride 72
    __shared__ unsigned short p_lds[4][2][16 * 72]; // per-wave, per-branch P tile
    __shared__ unsigned int sm_sh[TWG];

    int t0 = blockIdx.x * TWG;
    int tid = threadIdx.x;
    int wv = tid >> 6, ln = tid & 63;
    int c = ln & 15, g = ln >> 4;

    if (tid < TWG) sm_sh[tid] = selmask[t0 + tid];

    // Q A-fragments: lane row = c, k-slice = g*8+j, 4 K-steps
    bf16x8 qf[4];
    {
        int R = wv * 16 + c;
        int tq = t0 + (R >> 3), hq = R & 7;
        const float* qp = q + tq * 1024 + hq * 128;
        #pragma unroll
        for (int ks = 0; ks < 4; ++ks) {
            int d0 = ks * 32 + g * 8;
            float4 x = *reinterpret_cast<const float4*>(qp + d0);
            float4 y = *reinterpret_cast<const float4*>(qp + d0 + 4);
            bf16x8 f;
            f[0]=(short)f2bf(x.x); f[1]=(short)f2bf(x.y); f[2]=(short)f2bf(x.z); f[3]=(short)f2bf(x.w);
            f[4]=(short)f2bf(y.x); f[5]=(short)f2bf(y.y); f[6]=(short)f2bf(y.z); f[7]=(short)f2bf(y.w);
            qf[ks] = f;
        }
    }
    __syncthreads();

    // per-lane D-rows (m = g*4+i)
    int tt[4]; unsigned int sm[4];
    #pragma unroll
    for (int i = 0; i < 4; ++i) {
        int R = wv * 16 + g * 4 + i;
        tt[i] = t0 + (R >> 3);
        sm[i] = sm_sh[R >> 3];
    }
    unsigned int sm_wave = sm_sh[wv * 2] | sm_sh[wv * 2 + 1];
    unsigned int sm_union = 0;
    for (int i = 0; i < TWG; ++i) sm_union |= sm_sh[i];

    float m_run[2][4], l_run[2][4];
    f32x4 o_acc[2][8];
    #pragma unroll
    for (int br = 0; br < 2; ++br) {
        #pragma unroll
        for (int i = 0; i < 4; ++i) { m_run[br][i] = -1e30f; l_run[br][i] = 0.f; }
        #pragma unroll
        for (int nt = 0; nt < 8; ++nt) o_acc[br][nt] = (f32x4){0.f, 0.f, 0.f, 0.f};
    }

    int qblk_max = (t0 + TWG - 1) >> 6;
    int tw_min = t0 + wv * 2;

    for (int b = 0; b <= qblk_max; ++b) {
        bool blk_sel = (sm_union >> b) & 1u;          // uniform across WG
        bool blk_win = (b * 64 + 575 > t0);           // uniform across WG
        if (!blk_sel && !blk_win) continue;

        __syncthreads();  // previous block's LDS reads complete
        // stage K: bf16 row-major
        for (int i = tid; i < 2048; i += 256) {
            int row = i >> 5, d4 = (i & 31) << 2;
            float4 kv = *reinterpret_cast<const float4*>(k + (b * 64 + row) * 128 + d4);
            unsigned short* dst = k_lds + row * 136 + d4;
            dst[0] = f2bf(kv.x); dst[1] = f2bf(kv.y); dst[2] = f2bf(kv.z); dst[3] = f2bf(kv.w);
        }
        // stage V transposed: vt[n][p], packed pairs
        for (int i = tid; i < 4096; i += 256) {
            int n = i >> 5, pw = i & 31;
            float a  = v[(b * 64 + 2 * pw) * 128 + n];
            float bb = v[(b * 64 + 2 * pw + 1) * 128 + n];
            unsigned int wrd = (unsigned int)f2bf(a) | ((unsigned int)f2bf(bb) << 16);
            *reinterpret_cast<unsigned int*>(vt_lds + n * 72 + 2 * pw) = wrd;
        }
        __syncthreads();

        bool w_sel = (sm_wave >> b) & 1u;             // wave-uniform
        bool w_win = (b * 64 + 575 > tw_min);         // wave-uniform
        if (!w_sel && !w_win) continue;               // barriers already done

        // QK^T : S[m][pos] for this wave's 16 rows x 64 positions
        f32x4 sacc[4];
        #pragma unroll
        for (int nt = 0; nt < 4; ++nt) {
            f32x4 acc = (f32x4){0.f, 0.f, 0.f, 0.f};
            #pragma unroll
            for (int ks = 0; ks < 4; ++ks) {
                bf16x8 bfK = *reinterpret_cast<const bf16x8*>(
                    k_lds + (nt * 16 + c) * 136 + ks * 32 + g * 8);
                acc = __builtin_amdgcn_mfma_f32_16x16x32_bf16(qf[ks], bfK, acc, 0, 0, 0);
            }
            sacc[nt] = acc;
        }

        // online softmax per branch, P -> per-wave LDS
        float alpha[2][4];
        #pragma unroll
        for (int br = 0; br < 2; ++br) {
            bool active = (br == 0) ? w_sel : w_win;
            if (!active) {
                #pragma unroll
                for (int i = 0; i < 4; ++i) alpha[br][i] = 1.f;
            } else {
                #pragma unroll
                for (int i = 0; i < 4; ++i) {
                    float sval[4];
                    float mloc = -1e30f;
                    #pragma unroll
                    for (int nt = 0; nt < 4; ++nt) {
                        int pos = b * 64 + nt * 16 + c;
                        bool val;
                        if (br == 0) val = ((sm[i] >> b) & 1u) && (pos <= tt[i]);
                        else         val = (pos <= tt[i]) && (pos + 512 > tt[i]);
                        float s = val ? sacc[nt][i] * SCALE : -1e30f;
                        sval[nt] = s;
                        mloc = fmaxf(mloc, s);
                    }
                    #pragma unroll
                    for (int off = 1; off < 16; off <<= 1)
                        mloc = fmaxf(mloc, __shfl_xor(mloc, off));
                    float mo = m_run[br][i];
                    float mn = fmaxf(mo, mloc);
                    float al = expf(mo - mn);
                    float lsum = 0.f;
                    #pragma unroll
                    for (int nt = 0; nt < 4; ++nt) {
                        float p = (sval[nt] > -5e29f) ? expf(sval[nt] - mn) : 0.f;
                        lsum += p;
                        p_lds[wv][br][(g * 4 + i) * 72 + nt * 16 + c] = f2bf(p);
                    }
                    #pragma unroll
                    for (int off = 1; off < 16; off <<= 1) lsum += __shfl_xor(lsum, off);
                    m_run[br][i] = mn;
                    l_run[br][i] = l_run[br][i] * al + lsum;
                    alpha[br][i] = al;
                }
            }
        }
        // same-wave LDS write->read: drain writes, pin ordering
        asm volatile("s_waitcnt lgkmcnt(0)" ::: "memory");
        __builtin_amdgcn_sched_barrier(0);

        // rescale accumulators
        #pragma unroll
        for (int br = 0; br < 2; ++br)
            #pragma unroll
            for (int nt = 0; nt < 8; ++nt)
                #pragma unroll
                for (int i = 0; i < 4; ++i)
                    o_acc[br][nt][i] *= alpha[br][i];

        // P A-fragments
        bf16x8 af[2][2];
        #pragma unroll
        for (int br = 0; br < 2; ++br)
            #pragma unroll
            for (int ks = 0; ks < 2; ++ks)
                af[br][ks] = *reinterpret_cast<const bf16x8*>(
                    &p_lds[wv][br][c * 72 + ks * 32 + g * 8]);

        // PV: V B-frags shared across branches
        #pragma unroll
        for (int nt = 0; nt < 8; ++nt) {
            #pragma unroll
            for (int ks = 0; ks < 2; ++ks) {
                bf16x8 bfV = *reinterpret_cast<const bf16x8*>(
                    vt_lds + (nt * 16 + c) * 72 + ks * 32 + g * 8);
                if (w_sel) o_acc[0][nt] = __builtin_amdgcn_mfma_f32_16x16x32_bf16(af[0][ks], bfV, o_acc[0][nt], 0, 0, 0);
                if (w_win) o_acc[1][nt] = __builtin_amdgcn_mfma_f32_16x16x32_bf16(af[1][ks], bfV, o_acc[1][nt], 0, 0, 0);
            }
        }
    }

    // normalize
    #pragma unroll
    for (int br = 0; br < 2; ++br)
        #pragma unroll
        for (int i = 0; i < 4; ++i) {
            float inv = 1.f / l_run[br][i];
            #pragma unroll
            for (int nt = 0; nt < 8; ++nt) o_acc[br][nt][i] *= inv;
        }

    // fusion: gs = softmax(fw . [o_cmp|o_slc|o_sw]); out = sum gs_b * o_b
    #pragma unroll
    for (int i = 0; i < 4; ++i) {
        int R = wv * 16 + g * 4 + i;
        int th = t0 + (R >> 3), hh = R & 7;
        float oc[8];
        #pragma unroll
        for (int nt = 0; nt < 8; ++nt)
            oc[nt] = out[th * 1024 + hh * 128 + nt * 16 + c];  // o_cmp stored here by k_cmp_attn
        const float* fwp = fw + hh * 3 * 384;
        float p0 = 0.f, p1 = 0.f, p2 = 0.f;
        #pragma unroll
        for (int nt = 0; nt < 8; ++nt) {
            int d = nt * 16 + c;
            float a = oc[nt], bsl = o_acc[0][nt][i], cw = o_acc[1][nt][i];
            p0 += fwp[0 * 384 + d] * a + fwp[0 * 384 + 128 + d] * bsl + fwp[0 * 384 + 256 + d] * cw;
            p1 += fwp[1 * 384 + d] * a + fwp[1 * 384 + 128 + d] * bsl + fwp[1 * 384 + 256 + d] * cw;
            p2 += fwp[2 * 384 + d] * a + fwp[2 * 384 + 128 + d] * bsl + fwp[2 * 384 + 256 + d] * cw;
        }
        #pragma unroll
        for (int off = 1; off < 16; off <<= 1) {
            p0 += __shfl_xor(p0, off);
            p1 += __shfl_xor(p1, off);
            p2 += __shfl_xor(p2, off);
        }
        float mx = fmaxf(p0, fmaxf(p1, p2));
        float e0 = expf(p0 - mx), e1 = expf(p1 - mx), e2 = expf(p2 - mx);
        float inv = 1.f / (e0 + e1 + e2);
        float w0 = e0 * inv, w1 = e1 * inv, w2 = e2 * inv;
        #pragma unroll
        for (int nt = 0; nt < 8; ++nt) {
            out[th * 1024 + hh * 128 + nt * 16 + c] =
                w0 * oc[nt] + w1 * o_acc[0][nt][i] + w2 * o_acc[1][nt][i];
        }
    }
}

extern "C" void kernel_launch(void* const* d_in, const int* in_sizes, int n_in,
                              void* d_out, int out_size, void* d_ws, size_t ws_size,
                              hipStream_t stream) {
    (void)in_sizes; (void)n_in; (void)out_size; (void)ws_size;
    const float* q   = (const float*)d_in[0];
    const float* k   = (const float*)d_in[1];
    const float* v   = (const float*)d_in[2];
    const float* wk  = (const float*)d_in[3];
    const float* wvg = (const float*)d_in[4];
    const float* fw  = (const float*)d_in[5];
    float* out = (float*)d_out;
    float* ws = (float*)d_ws;
    // ws layout (floats): ck[127*128], cv[127*128], selmask[2048 u32]
    float* ck = ws;
    float* cv = ws + NCMP * 128;
    unsigned int* selmask = (unsigned int*)(ws + 2 * NCMP * 128);

    k_compress<<<dim3(NCMP), dim3(256), 0, stream>>>(k, wk, ck);
    k_compress<<<dim3(NCMP), dim3(256), 0, stream>>>(v, wvg, cv);
    // o_cmp goes directly into d_out; k_main reads it back then overwrites.
    k_cmp_attn<<<dim3(2048), dim3(256), 0, stream>>>(q, ck, cv, out, selmask);
    k_main<<<dim3(2048 / TWG), dim3(256), 0, stream>>>(q, k, v, selmask, fw, out);
}

// Round 2
// 466.074 us; speedup vs baseline: 1.4446x; 1.4446x over previous
//
#include <hip/hip_runtime.h>

// NSA constants
#define NCMP 127
#define SCALE 0.08838834764831845f
#define TWG 4   // t's per WG in k_main (2 pairs x 2 parity waves)
#define TB 8    // t's per WG in k_cmp_attn

typedef __attribute__((ext_vector_type(8))) short bf16x8;
typedef __attribute__((ext_vector_type(4))) float f32x4;

__device__ __forceinline__ unsigned short f2bf(float x) {
    union { float f; unsigned u; } a; a.f = x;
    unsigned r = a.u + 0x7fffu + ((a.u >> 16) & 1u);
    return (unsigned short)(r >> 16);
}
__device__ __forceinline__ float dot4(float4 a, float4 b) {
    return a.x * b.x + a.y * b.y + a.z * b.z + a.w * b.w;
}

// ---------------- Kernel A: compress (gate-pooled blocks) ----------------
__global__ __launch_bounds__(256) void k_compress(const float* __restrict__ src,
                                                  const float* __restrict__ w,
                                                  float* __restrict__ out) {
    __shared__ float blk[4096];   // 32 x 128
    __shared__ float gate[32];
    int n = blockIdx.x;
    int tid = threadIdx.x;
    const float* sp = src + n * 16 * 128;
    for (int i = tid; i < 4096; i += 256) blk[i] = sp[i];
    __syncthreads();
    int wv = tid >> 6, ln = tid & 63;
    for (int jj = 0; jj < 8; ++jj) {
        int j = wv * 8 + jj;
        const float* wp = w + j * 4096;
        float s = 0.f;
        for (int e = ln; e < 4096; e += 64) s += blk[e] * wp[e];
        #pragma unroll
        for (int off = 32; off > 0; off >>= 1) s += __shfl_xor(s, off);
        if (ln == 0) gate[j] = s;
    }
    __syncthreads();
    if (tid == 0) {
        float m = gate[0];
        for (int j = 1; j < 32; ++j) m = fmaxf(m, gate[j]);
        float ss = 0.f;
        for (int j = 0; j < 32; ++j) ss += expf(gate[j] - m);
        float inv = 1.f / ss;
        for (int j = 0; j < 32; ++j) gate[j] = expf(gate[j] - m) * inv;
    }
    __syncthreads();
    if (tid < 128) {
        float acc = 0.f;
        for (int kk = 0; kk < 32; ++kk) acc += gate[kk] * blk[kk * 128 + tid];
        out[n * 128 + tid] = acc;
    }
}

// ------------- Kernel D: f32 -> bf16 convert (K row-major, V transposed) -------------
__global__ __launch_bounds__(256) void k_convert(const float* __restrict__ k,
                                                 const float* __restrict__ v,
                                                 unsigned short* __restrict__ kbf,
                                                 unsigned short* __restrict__ vtbf) {
    int bid = blockIdx.x, tid = threadIdx.x;
    // kbf: 8 rows per WG, row-major [2048][128]
    {
        int idx = bid * 1024 + tid * 4;
        float4 x = *reinterpret_cast<const float4*>(k + idx);
        unsigned short o[4] = {f2bf(x.x), f2bf(x.y), f2bf(x.z), f2bf(x.w)};
        *reinterpret_cast<ulonglong1*>(kbf + idx) = *reinterpret_cast<ulonglong1*>(o);
    }
    // vtbf: [128][2048] (d-major). 8 positions per WG.
    {
        int p = bid * 8 + (tid >> 5);
        int d4 = (tid & 31) << 2;
        float4 x = *reinterpret_cast<const float4*>(v + p * 128 + d4);
        vtbf[(d4 + 0) * 2048 + p] = f2bf(x.x);
        vtbf[(d4 + 1) * 2048 + p] = f2bf(x.y);
        vtbf[(d4 + 2) * 2048 + p] = f2bf(x.z);
        vtbf[(d4 + 3) * 2048 + p] = f2bf(x.w);
    }
}

// ---------- Kernel B: compressed attention + top-k block select ----------
__global__ __launch_bounds__(256) void k_cmp_attn(const float* __restrict__ q,
                                                  const float* __restrict__ ck,
                                                  const float* __restrict__ cv,
                                                  float* __restrict__ o_cmp,
                                                  unsigned int* __restrict__ selmask) {
    __shared__ float sc[64 * 132];   // probs after softmax; stride 132
    __shared__ float pg[TB * 128];
    __shared__ float slc[TB * 32];
    __shared__ float adj[TB * 32];
    int t0 = blockIdx.x * TB;
    int tid = threadIdx.x;
    int wv = tid >> 6, ln = tid & 63;

    // ---- scores: q in regs (4 rows x 16 d / thread), ck streamed from L2 ----
    {
        int rh = wv >> 1, nh = wv & 1;         // row half / n half
        int rg = ln >> 3, ds = ln & 7;
        int d0 = ds * 16;
        float4 qr[4][4];
        #pragma unroll
        for (int rr = 0; rr < 4; ++rr) {
            int r = rh * 32 + rg * 4 + rr;
            const float4* qp = reinterpret_cast<const float4*>(
                q + (t0 + (r >> 3)) * 1024 + (r & 7) * 128 + d0);
            #pragma unroll
            for (int cc = 0; cc < 4; ++cc) qr[rr][cc] = qp[cc];
        }
        for (int jn = 0; jn < 64; ++jn) {
            int n = nh * 64 + jn;
            if (n >= NCMP) break;
            const float4* kp = reinterpret_cast<const float4*>(ck + n * 128 + d0);
            float4 k0 = kp[0], k1 = kp[1], k2 = kp[2], k3 = kp[3];
            float part[4];
            #pragma unroll
            for (int rr = 0; rr < 4; ++rr)
                part[rr] = dot4(qr[rr][0], k0) + dot4(qr[rr][1], k1) +
                           dot4(qr[rr][2], k2) + dot4(qr[rr][3], k3);
            #pragma unroll
            for (int off = 1; off < 8; off <<= 1)
                #pragma unroll
                for (int rr = 0; rr < 4; ++rr) part[rr] += __shfl_xor(part[rr], off);
            if (ds == 0) {
                #pragma unroll
                for (int rr = 0; rr < 4; ++rr)
                    sc[(rh * 32 + rg * 4 + rr) * 132 + n] = part[rr] * SCALE;
            }
        }
    }
    __syncthreads();

    // ---- mask + softmax per row (row = (t,h); 4 lanes per row) ----
    {
        int r = wv * 16 + (ln >> 2);
        int nl = ln & 3;
        int t = t0 + (r >> 3);
        int nvalid = (t >= 31) ? (((t - 31) >> 4) + 1) : 0;
        if (nvalid > NCMP) nvalid = NCMP;
        float* row = sc + r * 132;
        float m = -3e38f;
        for (int n = nl; n < nvalid; n += 4) m = fmaxf(m, row[n]);
        m = fmaxf(m, __shfl_xor(m, 1));
        m = fmaxf(m, __shfl_xor(m, 2));
        float ss = 0.f;
        for (int n = nl; n < 128; n += 4) {
            float e = (n < nvalid) ? expf(row[n] - m) : 0.f;
            ss += e;
            row[n] = e;
        }
        ss += __shfl_xor(ss, 1);
        ss += __shfl_xor(ss, 2);
        float inv = (ss > 0.f) ? 1.f / ss : 0.f;
        for (int n = nl; n < 128; n += 4) row[n] *= inv;
    }
    __syncthreads();

    // ---- o_cmp: p (LDS) . cv (L2 stream); 2 rows x 16 d per thread ----
    {
        int rg = ln >> 3, ds = ln & 7, d0 = ds * 16;
        int rbase = wv * 16 + rg * 2;
        int nvmax = (t0 + 7 >= 31) ? (((t0 + 7 - 31) >> 4) + 1) : 0;
        if (nvmax > NCMP) nvmax = NCMP;
        float4 acc[2][4];
        #pragma unroll
        for (int rr = 0; rr < 2; ++rr)
            #pragma unroll
            for (int cc = 0; cc < 4; ++cc) acc[rr][cc] = (float4){0.f, 0.f, 0.f, 0.f};
        for (int n = 0; n < nvmax; ++n) {
            const float4* vp = reinterpret_cast<const float4*>(cv + n * 128 + d0);
            float4 v0 = vp[0], v1 = vp[1], v2 = vp[2], v3 = vp[3];
            #pragma unroll
            for (int rr = 0; rr < 2; ++rr) {
                float p = sc[(rbase + rr) * 132 + n];
                acc[rr][0].x += p * v0.x; acc[rr][0].y += p * v0.y; acc[rr][0].z += p * v0.z; acc[rr][0].w += p * v0.w;
                acc[rr][1].x += p * v1.x; acc[rr][1].y += p * v1.y; acc[rr][1].z += p * v1.z; acc[rr][1].w += p * v1.w;
                acc[rr][2].x += p * v2.x; acc[rr][2].y += p * v2.y; acc[rr][2].z += p * v2.z; acc[rr][2].w += p * v2.w;
                acc[rr][3].x += p * v3.x; acc[rr][3].y += p * v3.y; acc[rr][3].z += p * v3.z; acc[rr][3].w += p * v3.w;
            }
        }
        #pragma unroll
        for (int rr = 0; rr < 2; ++rr) {
            int r = rbase + rr;
            float4* op = reinterpret_cast<float4*>(
                o_cmp + (t0 + (r >> 3)) * 1024 + (r & 7) * 128 + d0);
            #pragma unroll
            for (int cc = 0; cc < 4; ++cc) op[cc] = acc[rr][cc];
        }
    }

    // ---- pg: sum probs over heads ----
    for (int i2 = tid; i2 < TB * 128; i2 += 256) {
        int tl = i2 >> 7, n = i2 & 127;
        float s = 0.f;
        #pragma unroll
        for (int h = 0; h < 8; ++h) s += sc[(tl * 8 + h) * 132 + n];
        pg[i2] = s;
    }
    __syncthreads();
    if (tid < TB * 32) {
        int tl = tid >> 5, s32 = tid & 31;
        float s = 0.f;
        #pragma unroll
        for (int j = 0; j < 4; ++j) {
            int n = s32 * 4 + j;
            if (n < NCMP) s += pg[tl * 128 + n];
        }
        slc[tid] = s;
    }
    __syncthreads();
    if (tid < TB) {
        int t = t0 + tid;
        int qblk = t >> 6;
        float* a = adj + tid * 32;
        for (int s = 0; s < 32; ++s) {
            if (s > qblk) a[s] = -1e30f;
            else a[s] = slc[tid * 32 + s] + ((s == 0 || s > qblk - 2) ? 1e30f : 0.f);
        }
        unsigned int msk = 0u;
        for (int it = 0; it < 16; ++it) {
            float best = -2e38f; int bi = 0;
            for (int s = 0; s < 32; ++s) { if (a[s] > best) { best = a[s]; bi = s; } }
            if (best <= -5e29f) break;
            msk |= 1u << bi;
            a[bi] = -2e38f;
        }
        selmask[t] = msk;
    }
}

// -------- Kernel C: select + window attention, parity split-K, gate fusion --------
__global__ __launch_bounds__(256) void k_main(const float* __restrict__ q,
                                              const unsigned short* __restrict__ kbf,
                                              const unsigned short* __restrict__ vtbf,
                                              const unsigned int* __restrict__ selmask,
                                              const float* __restrict__ fw,
                                              float* __restrict__ out) {
    __shared__ unsigned short p_lds[4][2][16 * 72];   // per-wave P round-trip
    __shared__ float mrg[2][16 * 128];                // per-pair merge buffer (one branch at a time)
    __shared__ float mlbuf[2][2][16][2];              // pair, br, row, {m,l}

    int t0 = blockIdx.x * TWG;
    int tid = threadIdx.x;
    int wv = tid >> 6, ln = tid & 63;
    int pair = wv >> 1, par = wv & 1;
    int tp = t0 + pair * 2;
    int c = ln & 15, g = ln >> 4;

    unsigned int sm0 = selmask[tp], sm1 = selmask[tp + 1];
    unsigned int sm_wave = sm0 | sm1;

    // Q A-fragments (row c -> t = tp + (c>>3), h = c&7)
    bf16x8 qf[4];
    {
        const float* qp = q + (tp + (c >> 3)) * 1024 + (c & 7) * 128;
        #pragma unroll
        for (int ks = 0; ks < 4; ++ks) {
            int d0 = ks * 32 + g * 8;
            float4 x = *reinterpret_cast<const float4*>(qp + d0);
            float4 y = *reinterpret_cast<const float4*>(qp + d0 + 4);
            bf16x8 f;
            f[0]=(short)f2bf(x.x); f[1]=(short)f2bf(x.y); f[2]=(short)f2bf(x.z); f[3]=(short)f2bf(x.w);
            f[4]=(short)f2bf(y.x); f[5]=(short)f2bf(y.y); f[6]=(short)f2bf(y.z); f[7]=(short)f2bf(y.w);
            qf[ks] = f;
        }
    }

    int tt[4]; unsigned int smr[4];
    #pragma unroll
    for (int i = 0; i < 4; ++i) {
        int R = g * 4 + i;
        tt[i] = tp + (R >> 3);
        smr[i] = (R >> 3) ? sm1 : sm0;
    }

    float m_run[2][4], l_run[2][4];
    f32x4 o_acc[2][8];
    #pragma unroll
    for (int br = 0; br < 2; ++br) {
        #pragma unroll
        for (int i = 0; i < 4; ++i) { m_run[br][i] = -1e30f; l_run[br][i] = 0.f; }
        #pragma unroll
        for (int nt = 0; nt < 8; ++nt) o_acc[br][nt] = (f32x4){0.f, 0.f, 0.f, 0.f};
    }

    int qblk_max = (tp + 1) >> 6;

    for (int b = par; b <= qblk_max; b += 2) {
        bool w_sel = (sm_wave >> b) & 1u;
        bool w_win = (b * 64 + 575 > tp);
        if (!w_sel && !w_win) continue;

        // QK^T: direct bf16 fragment loads from global (L2-resident)
        f32x4 sacc[4];
        #pragma unroll
        for (int nt = 0; nt < 4; ++nt) {
            f32x4 acc = (f32x4){0.f, 0.f, 0.f, 0.f};
            #pragma unroll
            for (int ks = 0; ks < 4; ++ks) {
                bf16x8 bfK = *reinterpret_cast<const bf16x8*>(
                    kbf + (b * 64 + nt * 16 + c) * 128 + ks * 32 + g * 8);
                acc = __builtin_amdgcn_mfma_f32_16x16x32_bf16(qf[ks], bfK, acc, 0, 0, 0);
            }
            sacc[nt] = acc;
        }

        // online softmax per branch, P -> per-wave LDS
        float alpha[2][4];
        #pragma unroll
        for (int br = 0; br < 2; ++br) {
            bool active = (br == 0) ? w_sel : w_win;
            if (!active) {
                #pragma unroll
                for (int i = 0; i < 4; ++i) alpha[br][i] = 1.f;
            } else {
                #pragma unroll
                for (int i = 0; i < 4; ++i) {
                    float sval[4];
                    float mloc = -1e30f;
                    #pragma unroll
                    for (int nt = 0; nt < 4; ++nt) {
                        int pos = b * 64 + nt * 16 + c;
                        bool val;
                        if (br == 0) val = ((smr[i] >> b) & 1u) && (pos <= tt[i]);
                        else         val = (pos <= tt[i]) && (pos + 512 > tt[i]);
                        float s = val ? sacc[nt][i] * SCALE : -1e30f;
                        sval[nt] = s;
                        mloc = fmaxf(mloc, s);
                    }
                    #pragma unroll
                    for (int off = 1; off < 16; off <<= 1)
                        mloc = fmaxf(mloc, __shfl_xor(mloc, off));
                    float mo = m_run[br][i];
                    float mn = fmaxf(mo, mloc);
                    float al = expf(mo - mn);
                    float lsum = 0.f;
                    #pragma unroll
                    for (int nt = 0; nt < 4; ++nt) {
                        float p = (sval[nt] > -5e29f) ? expf(sval[nt] - mn) : 0.f;
                        lsum += p;
                        p_lds[wv][br][(g * 4 + i) * 72 + nt * 16 + c] = f2bf(p);
                    }
                    #pragma unroll
                    for (int off = 1; off < 16; off <<= 1) lsum += __shfl_xor(lsum, off);
                    m_run[br][i] = mn;
                    l_run[br][i] = l_run[br][i] * al + lsum;
                    alpha[br][i] = al;
                }
            }
        }
        // same-wave LDS write->read ordering
        asm volatile("s_waitcnt lgkmcnt(0)" ::: "memory");
        __builtin_amdgcn_sched_barrier(0);

        #pragma unroll
        for (int br = 0; br < 2; ++br)
            #pragma unroll
            for (int nt = 0; nt < 8; ++nt)
                #pragma unroll
                for (int i = 0; i < 4; ++i)
                    o_acc[br][nt][i] *= alpha[br][i];

        bf16x8 af[2][2];
        #pragma unroll
        for (int br = 0; br < 2; ++br)
            #pragma unroll
            for (int ks = 0; ks < 2; ++ks)
                af[br][ks] = *reinterpret_cast<const bf16x8*>(
                    &p_lds[wv][br][c * 72 + ks * 32 + g * 8]);

        #pragma unroll
        for (int nt = 0; nt < 8; ++nt) {
            #pragma unroll
            for (int ks = 0; ks < 2; ++ks) {
                bf16x8 bfV = *reinterpret_cast<const bf16x8*>(
                    vtbf + (nt * 16 + c) * 2048 + b * 64 + ks * 32 + g * 8);
                if (w_sel) o_acc[0][nt] = __builtin_amdgcn_mfma_f32_16x16x32_bf16(af[0][ks], bfV, o_acc[0][nt], 0, 0, 0);
                if (w_win) o_acc[1][nt] = __builtin_amdgcn_mfma_f32_16x16x32_bf16(af[1][ks], bfV, o_acc[1][nt], 0, 0, 0);
            }
        }
    }

    // ---- parity merge (flash-decode style) ----
    if (par == 1 && c == 0) {
        #pragma unroll
        for (int br = 0; br < 2; ++br)
            #pragma unroll
            for (int i = 0; i < 4; ++i) {
                mlbuf[pair][br][g * 4 + i][0] = m_run[br][i];
                mlbuf[pair][br][g * 4 + i][1] = l_run[br][i];
            }
    }
    #pragma unroll
    for (int br = 0; br < 2; ++br) {
        if (par == 1) {
            #pragma unroll
            for (int nt = 0; nt < 8; ++nt)
                #pragma unroll
                for (int i = 0; i < 4; ++i)
                    mrg[pair][(g * 4 + i) * 128 + nt * 16 + c] = o_acc[br][nt][i];
        }
        __syncthreads();
        if (par == 0) {
            #pragma unroll
            for (int i = 0; i < 4; ++i) {
                float m1 = mlbuf[pair][br][g * 4 + i][0];
                float l1 = mlbuf[pair][br][g * 4 + i][1];
                float m0 = m_run[br][i];
                float mn = fmaxf(m0, m1);
                float a0 = expf(m0 - mn), a1 = expf(m1 - mn);
                l_run[br][i] = a0 * l_run[br][i] + a1 * l1;
                #pragma unroll
                for (int nt = 0; nt < 8; ++nt)
                    o_acc[br][nt][i] = a0 * o_acc[br][nt][i] +
                                       a1 * mrg[pair][(g * 4 + i) * 128 + nt * 16 + c];
            }
        }
        __syncthreads();
    }
    if (par != 0) return;

    // normalize
    #pragma unroll
    for (int br = 0; br < 2; ++br)
        #pragma unroll
        for (int i = 0; i < 4; ++i) {
            float inv = 1.f / l_run[br][i];
            #pragma unroll
            for (int nt = 0; nt < 8; ++nt) o_acc[br][nt][i] *= inv;
        }

    // fusion epilogue
    #pragma unroll
    for (int i = 0; i < 4; ++i) {
        int R = g * 4 + i;
        int th = tp + (R >> 3), hh = R & 7;
        float oc[8];
        #pragma unroll
        for (int nt = 0; nt < 8; ++nt)
            oc[nt] = out[th * 1024 + hh * 128 + nt * 16 + c];
        const float* fwp = fw + hh * 3 * 384;
        float p0 = 0.f, p1 = 0.f, p2 = 0.f;
        #pragma unroll
        for (int nt = 0; nt < 8; ++nt) {
            int d = nt * 16 + c;
            float a = oc[nt], bsl = o_acc[0][nt][i], cw = o_acc[1][nt][i];
            p0 += fwp[0 * 384 + d] * a + fwp[0 * 384 + 128 + d] * bsl + fwp[0 * 384 + 256 + d] * cw;
            p1 += fwp[1 * 384 + d] * a + fwp[1 * 384 + 128 + d] * bsl + fwp[1 * 384 + 256 + d] * cw;
            p2 += fwp[2 * 384 + d] * a + fwp[2 * 384 + 128 + d] * bsl + fwp[2 * 384 + 256 + d] * cw;
        }
        #pragma unroll
        for (int off = 1; off < 16; off <<= 1) {
            p0 += __shfl_xor(p0, off);
            p1 += __shfl_xor(p1, off);
            p2 += __shfl_xor(p2, off);
        }
        float mx = fmaxf(p0, fmaxf(p1, p2));
        float e0 = expf(p0 - mx), e1 = expf(p1 - mx), e2 = expf(p2 - mx);
        float inv = 1.f / (e0 + e1 + e2);
        float w0 = e0 * inv, w1 = e1 * inv, w2 = e2 * inv;
        #pragma unroll
        for (int nt = 0; nt < 8; ++nt) {
            out[th * 1024 + hh * 128 + nt * 16 + c] =
                w0 * oc[nt] + w1 * o_acc[0][nt][i] + w2 * o_acc[1][nt][i];
        }
    }
}

extern "C" void kernel_launch(void* const* d_in, const int* in_sizes, int n_in,
                              void* d_out, int out_size, void* d_ws, size_t ws_size,
                              hipStream_t stream) {
    (void)in_sizes; (void)n_in; (void)out_size; (void)ws_size;
    const float* q   = (const float*)d_in[0];
    const float* k   = (const float*)d_in[1];
    const float* v   = (const float*)d_in[2];
    const float* wk  = (const float*)d_in[3];
    const float* wvg = (const float*)d_in[4];
    const float* fw  = (const float*)d_in[5];
    float* out = (float*)d_out;
    float* ws = (float*)d_ws;
    // ws layout: ck[127*128]f32, cv[127*128]f32, selmask[2048]u32,
    //            kbf[2048*128]bf16, vtbf[128*2048]bf16  (~1.2 MB total)
    float* ck = ws;
    float* cv = ws + NCMP * 128;
    unsigned int* selmask = (unsigned int*)(ws + 2 * NCMP * 128);
    unsigned short* kbf = (unsigned short*)(ws + 2 * NCMP * 128 + 2048);
    unsigned short* vtbf = kbf + 2048 * 128;

    k_compress<<<dim3(NCMP), dim3(256), 0, stream>>>(k, wk, ck);
    k_compress<<<dim3(NCMP), dim3(256), 0, stream>>>(v, wvg, cv);
    k_convert<<<dim3(256), dim3(256), 0, stream>>>(k, v, kbf, vtbf);
    k_cmp_attn<<<dim3(2048 / TB), dim3(256), 0, stream>>>(q, ck, cv, out, selmask);
    k_main<<<dim3(2048 / TWG), dim3(256), 0, stream>>>(q, kbf, vtbf, selmask, fw, out);
}

// Round 3
// 227.333 us; speedup vs baseline: 2.9616x; 2.0502x over previous
//
#include <hip/hip_runtime.h>

// NSA constants
#define NCMP 127
#define SCALE 0.08838834764831845f
#define TWG 4   // t's per WG in k_main (2 pairs x 2 parity waves)
#define TB 8    // t's per WG in k_cmp_attn

typedef __attribute__((ext_vector_type(8))) short bf16x8;
typedef __attribute__((ext_vector_type(4))) float f32x4;

__device__ __forceinline__ unsigned short f2bf(float x) {
    union { float f; unsigned u; } a; a.f = x;
    unsigned r = a.u + 0x7fffu + ((a.u >> 16) & 1u);
    return (unsigned short)(r >> 16);
}
__device__ __forceinline__ float dot4(float4 a, float4 b) {
    return a.x * b.x + a.y * b.y + a.z * b.z + a.w * b.w;
}

// ------------- Kernel A: fused k+v compress (gate-pooled blocks) -------------
// grid = 2*NCMP: even -> k/wk/ck, odd -> v/wv/cv
__global__ __launch_bounds__(256) void k_compress2(const float* __restrict__ kk,
                                                   const float* __restrict__ vv,
                                                   const float* __restrict__ wk,
                                                   const float* __restrict__ wv,
                                                   float* __restrict__ ck,
                                                   float* __restrict__ cv) {
    __shared__ float blk[4096];   // 32 x 128 f32
    __shared__ float gate[32];
    int n = blockIdx.x >> 1;
    int which = blockIdx.x & 1;
    const float* src = which ? vv : kk;
    const float* w   = which ? wv : wk;
    float* out       = which ? cv : ck;
    int tid = threadIdx.x;

    // stage block: 4096 floats = 1024 float4
    {
        const float4* sp = reinterpret_cast<const float4*>(src + n * 16 * 128);
        float4* bp = reinterpret_cast<float4*>(blk);
        #pragma unroll
        for (int i = 0; i < 4; ++i) bp[tid + 256 * i] = sp[tid + 256 * i];
    }
    __syncthreads();

    // gate logits: row j owned by 8 lanes, 4-wide float4 ILP
    {
        int j = tid >> 3, sub = tid & 7;
        const float4* wp = reinterpret_cast<const float4*>(w + j * 4096);
        const float4* bp = reinterpret_cast<const float4*>(blk);
        float s0 = 0.f, s1 = 0.f, s2 = 0.f, s3 = 0.f;
        for (int i = sub * 4; i < 1024; i += 32) {
            float4 w0 = wp[i], w1 = wp[i + 1], w2 = wp[i + 2], w3 = wp[i + 3];
            s0 += dot4(bp[i], w0);
            s1 += dot4(bp[i + 1], w1);
            s2 += dot4(bp[i + 2], w2);
            s3 += dot4(bp[i + 3], w3);
        }
        float s = (s0 + s1) + (s2 + s3);
        s += __shfl_xor(s, 1);
        s += __shfl_xor(s, 2);
        s += __shfl_xor(s, 4);
        if (sub == 0) gate[j] = s;
    }
    __syncthreads();

    // wave-parallel softmax over 32 gates (lanes 0..31)
    if (tid < 32) {
        float gv = gate[tid];
        float m = gv;
        #pragma unroll
        for (int off = 16; off > 0; off >>= 1) m = fmaxf(m, __shfl_xor(m, off));
        float e = expf(gv - m);
        float ss = e;
        #pragma unroll
        for (int off = 16; off > 0; off >>= 1) ss += __shfl_xor(ss, off);
        gate[tid] = e / ss;
    }
    __syncthreads();

    // weighted pool: out[d] = sum_kk gate[kk] * blk[kk*128+d]
    if (tid < 128) {
        float acc = 0.f;
        #pragma unroll
        for (int kx = 0; kx < 32; ++kx) acc += gate[kx] * blk[kx * 128 + tid];
        out[n * 128 + tid] = acc;
    }
}

// ------------- Kernel D: f32 -> bf16 convert (K row-major, V transposed) -------------
__global__ __launch_bounds__(256) void k_convert(const float* __restrict__ k,
                                                 const float* __restrict__ v,
                                                 unsigned short* __restrict__ kbf,
                                                 unsigned short* __restrict__ vtbf) {
    int bid = blockIdx.x, tid = threadIdx.x;
    // kbf: 8 rows per WG, row-major [2048][128]
    {
        int idx = bid * 1024 + tid * 4;
        float4 x = *reinterpret_cast<const float4*>(k + idx);
        unsigned short o[4] = {f2bf(x.x), f2bf(x.y), f2bf(x.z), f2bf(x.w)};
        *reinterpret_cast<ulonglong1*>(kbf + idx) = *reinterpret_cast<ulonglong1*>(o);
    }
    // vtbf: [128][2048] (d-major). 8 positions per WG.
    {
        int p = bid * 8 + (tid >> 5);
        int d4 = (tid & 31) << 2;
        float4 x = *reinterpret_cast<const float4*>(v + p * 128 + d4);
        vtbf[(d4 + 0) * 2048 + p] = f2bf(x.x);
        vtbf[(d4 + 1) * 2048 + p] = f2bf(x.y);
        vtbf[(d4 + 2) * 2048 + p] = f2bf(x.z);
        vtbf[(d4 + 3) * 2048 + p] = f2bf(x.w);
    }
}

// ---------- Kernel B: compressed attention + top-k block select ----------
__global__ __launch_bounds__(256) void k_cmp_attn(const float* __restrict__ q,
                                                  const float* __restrict__ ck,
                                                  const float* __restrict__ cv,
                                                  float* __restrict__ o_cmp,
                                                  unsigned int* __restrict__ selmask) {
    __shared__ float sc[64 * 132];   // probs after softmax; stride 132
    __shared__ float pg[TB * 128];
    __shared__ float slc[TB * 32];
    __shared__ float adj[TB * 32];
    int t0 = blockIdx.x * TB;
    int tid = threadIdx.x;
    int wv = tid >> 6, ln = tid & 63;

    // ---- scores: q in regs (4 rows x 16 d / thread), ck streamed from L2 ----
    {
        int rh = wv >> 1, nh = wv & 1;         // row half / n half
        int rg = ln >> 3, ds = ln & 7;
        int d0 = ds * 16;
        float4 qr[4][4];
        #pragma unroll
        for (int rr = 0; rr < 4; ++rr) {
            int r = rh * 32 + rg * 4 + rr;
            const float4* qp = reinterpret_cast<const float4*>(
                q + (t0 + (r >> 3)) * 1024 + (r & 7) * 128 + d0);
            #pragma unroll
            for (int cc = 0; cc < 4; ++cc) qr[rr][cc] = qp[cc];
        }
        for (int jn = 0; jn < 64; ++jn) {
            int n = nh * 64 + jn;
            if (n >= NCMP) break;
            const float4* kp = reinterpret_cast<const float4*>(ck + n * 128 + d0);
            float4 k0 = kp[0], k1 = kp[1], k2 = kp[2], k3 = kp[3];
            float part[4];
            #pragma unroll
            for (int rr = 0; rr < 4; ++rr)
                part[rr] = dot4(qr[rr][0], k0) + dot4(qr[rr][1], k1) +
                           dot4(qr[rr][2], k2) + dot4(qr[rr][3], k3);
            #pragma unroll
            for (int off = 1; off < 8; off <<= 1)
                #pragma unroll
                for (int rr = 0; rr < 4; ++rr) part[rr] += __shfl_xor(part[rr], off);
            if (ds == 0) {
                #pragma unroll
                for (int rr = 0; rr < 4; ++rr)
                    sc[(rh * 32 + rg * 4 + rr) * 132 + n] = part[rr] * SCALE;
            }
        }
    }
    __syncthreads();

    // ---- mask + softmax per row (row = (t,h); 4 lanes per row) ----
    {
        int r = wv * 16 + (ln >> 2);
        int nl = ln & 3;
        int t = t0 + (r >> 3);
        int nvalid = (t >= 31) ? (((t - 31) >> 4) + 1) : 0;
        if (nvalid > NCMP) nvalid = NCMP;
        float* row = sc + r * 132;
        float m = -3e38f;
        for (int n = nl; n < nvalid; n += 4) m = fmaxf(m, row[n]);
        m = fmaxf(m, __shfl_xor(m, 1));
        m = fmaxf(m, __shfl_xor(m, 2));
        float ss = 0.f;
        for (int n = nl; n < 128; n += 4) {
            float e = (n < nvalid) ? expf(row[n] - m) : 0.f;
            ss += e;
            row[n] = e;
        }
        ss += __shfl_xor(ss, 1);
        ss += __shfl_xor(ss, 2);
        float inv = (ss > 0.f) ? 1.f / ss : 0.f;
        for (int n = nl; n < 128; n += 4) row[n] *= inv;
    }
    __syncthreads();

    // ---- o_cmp: p (LDS) . cv (L2 stream); 2 rows x 16 d per thread ----
    {
        int rg = ln >> 3, ds = ln & 7, d0 = ds * 16;
        int rbase = wv * 16 + rg * 2;
        int nvmax = (t0 + 7 >= 31) ? (((t0 + 7 - 31) >> 4) + 1) : 0;
        if (nvmax > NCMP) nvmax = NCMP;
        float4 acc[2][4];
        #pragma unroll
        for (int rr = 0; rr < 2; ++rr)
            #pragma unroll
            for (int cc = 0; cc < 4; ++cc) acc[rr][cc] = (float4){0.f, 0.f, 0.f, 0.f};
        for (int n = 0; n < nvmax; ++n) {
            const float4* vp = reinterpret_cast<const float4*>(cv + n * 128 + d0);
            float4 v0 = vp[0], v1 = vp[1], v2 = vp[2], v3 = vp[3];
            #pragma unroll
            for (int rr = 0; rr < 2; ++rr) {
                float p = sc[(rbase + rr) * 132 + n];
                acc[rr][0].x += p * v0.x; acc[rr][0].y += p * v0.y; acc[rr][0].z += p * v0.z; acc[rr][0].w += p * v0.w;
                acc[rr][1].x += p * v1.x; acc[rr][1].y += p * v1.y; acc[rr][1].z += p * v1.z; acc[rr][1].w += p * v1.w;
                acc[rr][2].x += p * v2.x; acc[rr][2].y += p * v2.y; acc[rr][2].z += p * v2.z; acc[rr][2].w += p * v2.w;
                acc[rr][3].x += p * v3.x; acc[rr][3].y += p * v3.y; acc[rr][3].z += p * v3.z; acc[rr][3].w += p * v3.w;
            }
        }
        #pragma unroll
        for (int rr = 0; rr < 2; ++rr) {
            int r = rbase + rr;
            float4* op = reinterpret_cast<float4*>(
                o_cmp + (t0 + (r >> 3)) * 1024 + (r & 7) * 128 + d0);
            #pragma unroll
            for (int cc = 0; cc < 4; ++cc) op[cc] = acc[rr][cc];
        }
    }

    // ---- pg: sum probs over heads ----
    for (int i2 = tid; i2 < TB * 128; i2 += 256) {
        int tl = i2 >> 7, n = i2 & 127;
        float s = 0.f;
        #pragma unroll
        for (int h = 0; h < 8; ++h) s += sc[(tl * 8 + h) * 132 + n];
        pg[i2] = s;
    }
    __syncthreads();
    if (tid < TB * 32) {
        int tl = tid >> 5, s32 = tid & 31;
        float s = 0.f;
        #pragma unroll
        for (int j = 0; j < 4; ++j) {
            int n = s32 * 4 + j;
            if (n < NCMP) s += pg[tl * 128 + n];
        }
        slc[tid] = s;
    }
    __syncthreads();
    if (tid < TB) {
        int t = t0 + tid;
        int qblk = t >> 6;
        float* a = adj + tid * 32;
        for (int s = 0; s < 32; ++s) {
            if (s > qblk) a[s] = -1e30f;
            else a[s] = slc[tid * 32 + s] + ((s == 0 || s > qblk - 2) ? 1e30f : 0.f);
        }
        unsigned int msk = 0u;
        for (int it = 0; it < 16; ++it) {
            float best = -2e38f; int bi = 0;
            for (int s = 0; s < 32; ++s) { if (a[s] > best) { best = a[s]; bi = s; } }
            if (best <= -5e29f) break;
            msk |= 1u << bi;
            a[bi] = -2e38f;
        }
        selmask[t] = msk;
    }
}

// -------- Kernel C: select + window attention, parity split-K, gate fusion --------
__global__ __launch_bounds__(256) void k_main(const float* __restrict__ q,
                                              const unsigned short* __restrict__ kbf,
                                              const unsigned short* __restrict__ vtbf,
                                              const unsigned int* __restrict__ selmask,
                                              const float* __restrict__ fw,
                                              float* __restrict__ out) {
    __shared__ unsigned short p_lds[4][2][16 * 72];   // per-wave P round-trip
    __shared__ float mrg[2][16 * 128];                // per-pair merge buffer (one branch at a time)
    __shared__ float mlbuf[2][2][16][2];              // pair, br, row, {m,l}

    int t0 = blockIdx.x * TWG;
    int tid = threadIdx.x;
    int wv = tid >> 6, ln = tid & 63;
    int pair = wv >> 1, par = wv & 1;
    int tp = t0 + pair * 2;
    int c = ln & 15, g = ln >> 4;

    unsigned int sm0 = selmask[tp], sm1 = selmask[tp + 1];
    unsigned int sm_wave = sm0 | sm1;

    // Q A-fragments (row c -> t = tp + (c>>3), h = c&7)
    bf16x8 qf[4];
    {
        const float* qp = q + (tp + (c >> 3)) * 1024 + (c & 7) * 128;
        #pragma unroll
        for (int ks = 0; ks < 4; ++ks) {
            int d0 = ks * 32 + g * 8;
            float4 x = *reinterpret_cast<const float4*>(qp + d0);
            float4 y = *reinterpret_cast<const float4*>(qp + d0 + 4);
            bf16x8 f;
            f[0]=(short)f2bf(x.x); f[1]=(short)f2bf(x.y); f[2]=(short)f2bf(x.z); f[3]=(short)f2bf(x.w);
            f[4]=(short)f2bf(y.x); f[5]=(short)f2bf(y.y); f[6]=(short)f2bf(y.z); f[7]=(short)f2bf(y.w);
            qf[ks] = f;
        }
    }

    int tt[4]; unsigned int smr[4];
    #pragma unroll
    for (int i = 0; i < 4; ++i) {
        int R = g * 4 + i;
        tt[i] = tp + (R >> 3);
        smr[i] = (R >> 3) ? sm1 : sm0;
    }

    float m_run[2][4], l_run[2][4];
    f32x4 o_acc[2][8];
    #pragma unroll
    for (int br = 0; br < 2; ++br) {
        #pragma unroll
        for (int i = 0; i < 4; ++i) { m_run[br][i] = -1e30f; l_run[br][i] = 0.f; }
        #pragma unroll
        for (int nt = 0; nt < 8; ++nt) o_acc[br][nt] = (f32x4){0.f, 0.f, 0.f, 0.f};
    }

    int qblk_max = (tp + 1) >> 6;

    for (int b = par; b <= qblk_max; b += 2) {
        bool w_sel = (sm_wave >> b) & 1u;
        bool w_win = (b * 64 + 575 > tp);
        if (!w_sel && !w_win) continue;

        // QK^T: direct bf16 fragment loads from global (L2-resident)
        f32x4 sacc[4];
        #pragma unroll
        for (int nt = 0; nt < 4; ++nt) {
            f32x4 acc = (f32x4){0.f, 0.f, 0.f, 0.f};
            #pragma unroll
            for (int ks = 0; ks < 4; ++ks) {
                bf16x8 bfK = *reinterpret_cast<const bf16x8*>(
                    kbf + (b * 64 + nt * 16 + c) * 128 + ks * 32 + g * 8);
                acc = __builtin_amdgcn_mfma_f32_16x16x32_bf16(qf[ks], bfK, acc, 0, 0, 0);
            }
            sacc[nt] = acc;
        }

        // online softmax per branch, P -> per-wave LDS
        float alpha[2][4];
        #pragma unroll
        for (int br = 0; br < 2; ++br) {
            bool active = (br == 0) ? w_sel : w_win;
            if (!active) {
                #pragma unroll
                for (int i = 0; i < 4; ++i) alpha[br][i] = 1.f;
            } else {
                #pragma unroll
                for (int i = 0; i < 4; ++i) {
                    float sval[4];
                    float mloc = -1e30f;
                    #pragma unroll
                    for (int nt = 0; nt < 4; ++nt) {
                        int pos = b * 64 + nt * 16 + c;
                        bool val;
                        if (br == 0) val = ((smr[i] >> b) & 1u) && (pos <= tt[i]);
                        else         val = (pos <= tt[i]) && (pos + 512 > tt[i]);
                        float s = val ? sacc[nt][i] * SCALE : -1e30f;
                        sval[nt] = s;
                        mloc = fmaxf(mloc, s);
                    }
                    #pragma unroll
                    for (int off = 1; off < 16; off <<= 1)
                        mloc = fmaxf(mloc, __shfl_xor(mloc, off));
                    float mo = m_run[br][i];
                    float mn = fmaxf(mo, mloc);
                    float al = expf(mo - mn);
                    float lsum = 0.f;
                    #pragma unroll
                    for (int nt = 0; nt < 4; ++nt) {
                        float p = (sval[nt] > -5e29f) ? expf(sval[nt] - mn) : 0.f;
                        lsum += p;
                        p_lds[wv][br][(g * 4 + i) * 72 + nt * 16 + c] = f2bf(p);
                    }
                    #pragma unroll
                    for (int off = 1; off < 16; off <<= 1) lsum += __shfl_xor(lsum, off);
                    m_run[br][i] = mn;
                    l_run[br][i] = l_run[br][i] * al + lsum;
                    alpha[br][i] = al;
                }
            }
        }
        // same-wave LDS write->read ordering
        asm volatile("s_waitcnt lgkmcnt(0)" ::: "memory");
        __builtin_amdgcn_sched_barrier(0);

        #pragma unroll
        for (int br = 0; br < 2; ++br)
            #pragma unroll
            for (int nt = 0; nt < 8; ++nt)
                #pragma unroll
                for (int i = 0; i < 4; ++i)
                    o_acc[br][nt][i] *= alpha[br][i];

        bf16x8 af[2][2];
        #pragma unroll
        for (int br = 0; br < 2; ++br)
            #pragma unroll
            for (int ks = 0; ks < 2; ++ks)
                af[br][ks] = *reinterpret_cast<const bf16x8*>(
                    &p_lds[wv][br][c * 72 + ks * 32 + g * 8]);

        #pragma unroll
        for (int nt = 0; nt < 8; ++nt) {
            #pragma unroll
            for (int ks = 0; ks < 2; ++ks) {
                bf16x8 bfV = *reinterpret_cast<const bf16x8*>(
                    vtbf + (nt * 16 + c) * 2048 + b * 64 + ks * 32 + g * 8);
                if (w_sel) o_acc[0][nt] = __builtin_amdgcn_mfma_f32_16x16x32_bf16(af[0][ks], bfV, o_acc[0][nt], 0, 0, 0);
                if (w_win) o_acc[1][nt] = __builtin_amdgcn_mfma_f32_16x16x32_bf16(af[1][ks], bfV, o_acc[1][nt], 0, 0, 0);
            }
        }
    }

    // ---- parity merge (flash-decode style) ----
    if (par == 1 && c == 0) {
        #pragma unroll
        for (int br = 0; br < 2; ++br)
            #pragma unroll
            for (int i = 0; i < 4; ++i) {
                mlbuf[pair][br][g * 4 + i][0] = m_run[br][i];
                mlbuf[pair][br][g * 4 + i][1] = l_run[br][i];
            }
    }
    #pragma unroll
    for (int br = 0; br < 2; ++br) {
        if (par == 1) {
            #pragma unroll
            for (int nt = 0; nt < 8; ++nt)
                #pragma unroll
                for (int i = 0; i < 4; ++i)
                    mrg[pair][(g * 4 + i) * 128 + nt * 16 + c] = o_acc[br][nt][i];
        }
        __syncthreads();
        if (par == 0) {
            #pragma unroll
            for (int i = 0; i < 4; ++i) {
                float m1 = mlbuf[pair][br][g * 4 + i][0];
                float l1 = mlbuf[pair][br][g * 4 + i][1];
                float m0 = m_run[br][i];
                float mn = fmaxf(m0, m1);
                float a0 = expf(m0 - mn), a1 = expf(m1 - mn);
                l_run[br][i] = a0 * l_run[br][i] + a1 * l1;
                #pragma unroll
                for (int nt = 0; nt < 8; ++nt)
                    o_acc[br][nt][i] = a0 * o_acc[br][nt][i] +
                                       a1 * mrg[pair][(g * 4 + i) * 128 + nt * 16 + c];
            }
        }
        __syncthreads();
    }
    if (par != 0) return;

    // normalize
    #pragma unroll
    for (int br = 0; br < 2; ++br)
        #pragma unroll
        for (int i = 0; i < 4; ++i) {
            float inv = 1.f / l_run[br][i];
            #pragma unroll
            for (int nt = 0; nt < 8; ++nt) o_acc[br][nt][i] *= inv;
        }

    // fusion epilogue
    #pragma unroll
    for (int i = 0; i < 4; ++i) {
        int R = g * 4 + i;
        int th = tp + (R >> 3), hh = R & 7;
        float oc[8];
        #pragma unroll
        for (int nt = 0; nt < 8; ++nt)
            oc[nt] = out[th * 1024 + hh * 128 + nt * 16 + c];
        const float* fwp = fw + hh * 3 * 384;
        float p0 = 0.f, p1 = 0.f, p2 = 0.f;
        #pragma unroll
        for (int nt = 0; nt < 8; ++nt) {
            int d = nt * 16 + c;
            float a = oc[nt], bsl = o_acc[0][nt][i], cw = o_acc[1][nt][i];
            p0 += fwp[0 * 384 + d] * a + fwp[0 * 384 + 128 + d] * bsl + fwp[0 * 384 + 256 + d] * cw;
            p1 += fwp[1 * 384 + d] * a + fwp[1 * 384 + 128 + d] * bsl + fwp[1 * 384 + 256 + d] * cw;
            p2 += fwp[2 * 384 + d] * a + fwp[2 * 384 + 128 + d] * bsl + fwp[2 * 384 + 256 + d] * cw;
        }
        #pragma unroll
        for (int off = 1; off < 16; off <<= 1) {
            p0 += __shfl_xor(p0, off);
            p1 += __shfl_xor(p1, off);
            p2 += __shfl_xor(p2, off);
        }
        float mx = fmaxf(p0, fmaxf(p1, p2));
        float e0 = expf(p0 - mx), e1 = expf(p1 - mx), e2 = expf(p2 - mx);
        float inv = 1.f / (e0 + e1 + e2);
        float w0 = e0 * inv, w1 = e1 * inv, w2 = e2 * inv;
        #pragma unroll
        for (int nt = 0; nt < 8; ++nt) {
            out[th * 1024 + hh * 128 + nt * 16 + c] =
                w0 * oc[nt] + w1 * o_acc[0][nt][i] + w2 * o_acc[1][nt][i];
        }
    }
}

extern "C" void kernel_launch(void* const* d_in, const int* in_sizes, int n_in,
                              void* d_out, int out_size, void* d_ws, size_t ws_size,
                              hipStream_t stream) {
    (void)in_sizes; (void)n_in; (void)out_size; (void)ws_size;
    const float* q   = (const float*)d_in[0];
    const float* k   = (const float*)d_in[1];
    const float* v   = (const float*)d_in[2];
    const float* wk  = (const float*)d_in[3];
    const float* wvg = (const float*)d_in[4];
    const float* fw  = (const float*)d_in[5];
    float* out = (float*)d_out;
    float* ws = (float*)d_ws;
    // ws layout: ck[127*128]f32, cv[127*128]f32, selmask[2048]u32,
    //            kbf[2048*128]bf16, vtbf[128*2048]bf16  (~1.2 MB total)
    float* ck = ws;
    float* cv = ws + NCMP * 128;
    unsigned int* selmask = (unsigned int*)(ws + 2 * NCMP * 128);
    unsigned short* kbf = (unsigned short*)(ws + 2 * NCMP * 128 + 2048);
    unsigned short* vtbf = kbf + 2048 * 128;

    k_convert<<<dim3(256), dim3(256), 0, stream>>>(k, v, kbf, vtbf);
    k_compress2<<<dim3(2 * NCMP), dim3(256), 0, stream>>>(k, v, wk, wvg, ck, cv);
    k_cmp_attn<<<dim3(2048 / TB), dim3(256), 0, stream>>>(q, ck, cv, out, selmask);
    k_main<<<dim3(2048 / TWG), dim3(256), 0, stream>>>(q, kbf, vtbf, selmask, fw, out);
}